// Round 1
// baseline (204.449 us; speedup 1.0000x reference)
//
#include <hip/hip_runtime.h>
#include <hip/hip_bf16.h>

// Problem-fixed shapes: features [4,64,2048] fp32 (viewed as feats[m][c] =
// flat[c*8192+m]), labels [8192] int, NUM_CLASSES=4, TEMP=0.07, scalar fp32 out.
#define M_TOT 8192
#define NCLS 4

// ---------------- JAX threefry-2x32, key = PRNGKey(42) = (0, 42) -------------
__device__ __forceinline__ unsigned int rotl32(unsigned int x, unsigned int r) {
    return (x << r) | (x >> (32u - r));
}

// Reproduces bits = threefry_2x32((0,42), iota(u32, 8192))[m].
// JAX splits iota into halves: pair j = (m mod 4096) processes counts
// (j, j+4096); output is concat(x0_final, x1_final).
__device__ unsigned int threefry_bits_key42(unsigned int m) {
    const unsigned int ks0 = 0u;
    const unsigned int ks1 = 42u;
    const unsigned int ks2 = 0x1BD11BDAu ^ 0u ^ 42u;
    unsigned int j  = (m < 4096u) ? m : (m - 4096u);
    unsigned int x0 = j + ks0;
    unsigned int x1 = (j + 4096u) + ks1;
#define TF_RND(r) { x0 += x1; x1 = rotl32(x1, (r)); x1 ^= x0; }
    TF_RND(13u) TF_RND(15u) TF_RND(26u) TF_RND(6u)
    x0 += ks1; x1 += ks2 + 1u;
    TF_RND(17u) TF_RND(29u) TF_RND(16u) TF_RND(24u)
    x0 += ks2; x1 += ks0 + 2u;
    TF_RND(13u) TF_RND(15u) TF_RND(26u) TF_RND(6u)
    x0 += ks0; x1 += ks1 + 3u;
    TF_RND(17u) TF_RND(29u) TF_RND(16u) TF_RND(24u)
    x0 += ks1; x1 += ks2 + 4u;
    TF_RND(13u) TF_RND(15u) TF_RND(26u) TF_RND(6u)
    x0 += ks2; x1 += ks0 + 5u;
#undef TF_RND
    return (m < 4096u) ? x0 : x1;
}

// ---------------- kernel 1: histogram, selection, compaction -----------------
__global__ void setup_kernel(const int* __restrict__ labels,
                             int* __restrict__ nsel_g,
                             int* __restrict__ sel_idx,
                             int* __restrict__ lab_sel,
                             float* __restrict__ pos,
                             float* __restrict__ neg) {
    __shared__ int   hist[NCLS];
    __shared__ float keepp[NCLS];
    __shared__ int   tcnt[256];
    __shared__ int   tbase[256];
    const int t = threadIdx.x;
    if (t < NCLS) hist[t] = 0;
    __syncthreads();
    for (int m = t; m < M_TOT; m += 256) atomicAdd(&hist[labels[m]], 1);
    __syncthreads();
    if (t < NCLS) keepp[t] = fminf(750.0f / ((float)hist[t] + 1.0f), 1.0f);
    __syncthreads();

    // each thread owns 32 contiguous m values
    const int m0 = t * 32;
    unsigned int flags = 0u;
    int cnt = 0;
    for (int r = 0; r < 32; ++r) {
        const int m = m0 + r;
        const unsigned int bits = threefry_bits_key42((unsigned int)m);
        // JAX uniform: bitcast((bits>>9)|0x3F800000) - 1.0, then  u < p  (strict)
        const float u = __uint_as_float((bits >> 9) | 0x3F800000u) - 1.0f;
        const int lab = labels[m];
        if (u < keepp[lab]) { flags |= (1u << r); ++cnt; }
    }
    tcnt[t] = cnt;
    __syncthreads();
    if (t == 0) {
        int run = 0;
        for (int i = 0; i < 256; ++i) { tbase[i] = run; run += tcnt[i]; }
        *nsel_g = run;
    }
    __syncthreads();
    int base = tbase[t];
    for (int r = 0; r < 32; ++r) {
        if (flags & (1u << r)) {
            const int m = m0 + r;
            sel_idx[base] = m;
            lab_sel[base] = labels[m];
            ++base;
        }
    }
    // zero accumulators (ws is poisoned 0xAA each call)
    for (int i = t; i < M_TOT; i += 256) { pos[i] = 0.0f; neg[i] = 0.0f; }
}

// ---------------- kernel 2: L2-normalize selected rows, store transposed -----
// nv_t[k * 8192 + i] = feats[sel_idx[i]][k] / ||feats[sel_idx[i]]||
__global__ void norm_kernel(const float* __restrict__ features,
                            const int* __restrict__ sel_idx,
                            const int* __restrict__ nsel_g,
                            float* __restrict__ nv_t) {
    const int i = blockIdx.x * 256 + threadIdx.x;
    if (i >= M_TOT) return;
    const int nsel = *nsel_g;
    if (i >= nsel) {  // zero-pad so tile loads stay finite (masked later anyway)
        #pragma unroll
        for (int k = 0; k < 64; ++k) nv_t[k * M_TOT + i] = 0.0f;
        return;
    }
    const int m = sel_idx[i];
    float v[64];
    float ss = 0.0f;
    #pragma unroll
    for (int k = 0; k < 64; ++k) {
        v[k] = features[k * M_TOT + m];
        ss += v[k] * v[k];
    }
    const float rn = rsqrtf(ss);
    #pragma unroll
    for (int k = 0; k < 64; ++k) nv_t[k * M_TOT + i] = v[k] * rn;
}

// ---------------- kernel 3: pairwise exp-sim masked row sums -----------------
// 64x64 tile per block, 256 threads, 4x4 results/thread, fp32 vector FMA.
__global__ __launch_bounds__(256) void pair_kernel(
        const float* __restrict__ nv_t,
        const int* __restrict__ lab_sel,
        const int* __restrict__ nsel_g,
        float* __restrict__ pos,
        float* __restrict__ neg) {
    const int nsel = *nsel_g;
    const int i0 = blockIdx.y * 64;
    const int j0 = blockIdx.x * 64;
    if (i0 >= nsel || j0 >= nsel) return;

    __shared__ float As[64][64];   // [k][i]  (k-major: fragment reads are float4)
    __shared__ float Bs[64][64];   // [k][j]
    __shared__ int   La[64], Lb[64];

    const int t = threadIdx.x;
    #pragma unroll
    for (int r = 0; r < 4; ++r) {
        const int idx = r * 256 + t;        // 0..1023 float4 slots
        const int k   = idx >> 4;
        const int c4  = (idx & 15) * 4;
        *(float4*)&As[k][c4] = *(const float4*)&nv_t[k * M_TOT + i0 + c4];
        *(float4*)&Bs[k][c4] = *(const float4*)&nv_t[k * M_TOT + j0 + c4];
    }
    if (t < 64)       La[t]      = (i0 + t < nsel)        ? lab_sel[i0 + t]      : -1;
    else if (t < 128) Lb[t - 64] = (j0 + (t - 64) < nsel) ? lab_sel[j0 + t - 64] : -2;
    __syncthreads();

    const int tx = t & 15, ty = t >> 4;
    float acc[4][4] = {};
    #pragma unroll
    for (int k = 0; k < 64; ++k) {
        const float4 a = *(const float4*)&As[k][ty * 4];
        const float4 b = *(const float4*)&Bs[k][tx * 4];
        const float av[4] = {a.x, a.y, a.z, a.w};
        const float bv[4] = {b.x, b.y, b.z, b.w};
        #pragma unroll
        for (int aa = 0; aa < 4; ++aa)
            #pragma unroll
            for (int bb = 0; bb < 4; ++bb)
                acc[aa][bb] += av[aa] * bv[bb];
    }

    const float invT = 1.0f / 0.07f;
    float pacc[4] = {0, 0, 0, 0}, nacc[4] = {0, 0, 0, 0};
    #pragma unroll
    for (int aa = 0; aa < 4; ++aa) {
        const int ig = i0 + ty * 4 + aa;
        const int Li = La[ty * 4 + aa];
        #pragma unroll
        for (int bb = 0; bb < 4; ++bb) {
            const int jg = j0 + tx * 4 + bb;
            const bool valid = (ig < nsel) && (jg < nsel) && (ig != jg);
            const float d = valid ? expf(acc[aa][bb] * invT) : 0.0f;
            if (Li == Lb[tx * 4 + bb]) pacc[aa] += d; else nacc[aa] += d;
        }
    }

    // reduce across the 16 lanes sharing an i-row (tx dimension)
    #pragma unroll
    for (int aa = 0; aa < 4; ++aa) {
        float p = pacc[aa], n = nacc[aa];
        for (int off = 8; off > 0; off >>= 1) {
            p += __shfl_down(p, off, 16);
            n += __shfl_down(n, off, 16);
        }
        if (tx == 0) {
            const int ig = i0 + ty * 4 + aa;
            if (ig < nsel) {
                atomicAdd(&pos[ig], p);
                atomicAdd(&neg[ig], n);
            }
        }
    }
}

// ---------------- kernel 4: final loss reduction -----------------------------
__global__ void loss_kernel(const float* __restrict__ pos,
                            const float* __restrict__ neg,
                            const int* __restrict__ nsel_g,
                            float* __restrict__ out) {
    const int nsel = *nsel_g;
    float s = 0.0f;
    for (int i = threadIdx.x; i < nsel; i += 256) {
        const float fr = pos[i] / (pos[i] + neg[i]);
        s += -logf(fr);
    }
    __shared__ float red[256];
    red[threadIdx.x] = s;
    __syncthreads();
    for (int off = 128; off > 0; off >>= 1) {
        if (threadIdx.x < off) red[threadIdx.x] += red[threadIdx.x + off];
        __syncthreads();
    }
    if (threadIdx.x == 0) out[0] = red[0] / (float)(nsel > 0 ? nsel : 1);
}

// ---------------- launch -----------------------------------------------------
extern "C" void kernel_launch(void* const* d_in, const int* in_sizes, int n_in,
                              void* d_out, int out_size, void* d_ws, size_t ws_size,
                              hipStream_t stream) {
    const float* features = (const float*)d_in[0];
    const int*   labels   = (const int*)d_in[1];
    float*       out      = (float*)d_out;
    char*        ws       = (char*)d_ws;

    int*   nsel_g  = (int*)(ws + 16);
    int*   sel_idx = (int*)(ws + 64);
    int*   lab_sel = (int*)(ws + 64 + 32768);
    float* pos     = (float*)(ws + 64 + 65536);
    float* neg     = pos + M_TOT;
    float* nv_t    = (float*)(ws + 64 + 65536 + 65536);   // 64*8192 fp32 = 2 MiB

    setup_kernel<<<1, 256, 0, stream>>>(labels, nsel_g, sel_idx, lab_sel, pos, neg);
    norm_kernel<<<M_TOT / 256, 256, 0, stream>>>(features, sel_idx, nsel_g, nv_t);
    pair_kernel<<<dim3(M_TOT / 64, M_TOT / 64), 256, 0, stream>>>(nv_t, lab_sel, nsel_g, pos, neg);
    loss_kernel<<<1, 256, 0, stream>>>(pos, neg, nsel_g, out);
}

// Round 2
// 115.185 us; speedup vs baseline: 1.7750x; 1.7750x over previous
//
#include <hip/hip_runtime.h>
#include <hip/hip_bf16.h>

// Problem-fixed shapes: features [4,64,2048] fp32 (viewed as feats[m][c] =
// flat[c*8192+m]), labels [8192] int, NUM_CLASSES=4, TEMP=0.07, scalar fp32 out.
#define M_TOT 8192
#define NCLS 4
#define TMAX 64          // 64 tiles of 64 = covers nsel <= 4096 (nsel ~ 3000, >25 sigma margin)

// ---------------- JAX threefry-2x32, key = PRNGKey(42) = (0, 42) -------------
__device__ __forceinline__ unsigned int rotl32(unsigned int x, unsigned int r) {
    return (x << r) | (x >> (32u - r));
}

__device__ unsigned int threefry_bits_key42(unsigned int m) {
    const unsigned int ks0 = 0u;
    const unsigned int ks1 = 42u;
    const unsigned int ks2 = 0x1BD11BDAu ^ 0u ^ 42u;
    unsigned int j  = (m < 4096u) ? m : (m - 4096u);
    unsigned int x0 = j + ks0;
    unsigned int x1 = (j + 4096u) + ks1;
#define TF_RND(r) { x0 += x1; x1 = rotl32(x1, (r)); x1 ^= x0; }
    TF_RND(13u) TF_RND(15u) TF_RND(26u) TF_RND(6u)
    x0 += ks1; x1 += ks2 + 1u;
    TF_RND(17u) TF_RND(29u) TF_RND(16u) TF_RND(24u)
    x0 += ks2; x1 += ks0 + 2u;
    TF_RND(13u) TF_RND(15u) TF_RND(26u) TF_RND(6u)
    x0 += ks0; x1 += ks1 + 3u;
    TF_RND(17u) TF_RND(29u) TF_RND(16u) TF_RND(24u)
    x0 += ks1; x1 += ks2 + 4u;
    TF_RND(13u) TF_RND(15u) TF_RND(26u) TF_RND(6u)
    x0 += ks2; x1 += ks0 + 5u;
#undef TF_RND
    return (m < 4096u) ? x0 : x1;
}

// ---------------- kernel 1: histogram, selection, compaction -----------------
__global__ void setup_kernel(const int* __restrict__ labels,
                             int* __restrict__ nsel_g,
                             int* __restrict__ sel_idx,
                             int* __restrict__ lab_sel,
                             float* __restrict__ pos,
                             float* __restrict__ neg) {
    __shared__ int   hist[NCLS];
    __shared__ float keepp[NCLS];
    __shared__ int   tcnt[256];
    __shared__ int   tbase[256];
    const int t = threadIdx.x;
    if (t < NCLS) hist[t] = 0;
    __syncthreads();
    for (int m = t; m < M_TOT; m += 256) atomicAdd(&hist[labels[m]], 1);
    __syncthreads();
    if (t < NCLS) keepp[t] = fminf(750.0f / ((float)hist[t] + 1.0f), 1.0f);
    __syncthreads();

    const int m0 = t * 32;
    unsigned int flags = 0u;
    int cnt = 0;
    for (int r = 0; r < 32; ++r) {
        const int m = m0 + r;
        const unsigned int bits = threefry_bits_key42((unsigned int)m);
        // JAX uniform: bitcast((bits>>9)|0x3F800000) - 1.0, then u < p (strict)
        const float u = __uint_as_float((bits >> 9) | 0x3F800000u) - 1.0f;
        const int lab = labels[m];
        if (u < keepp[lab]) { flags |= (1u << r); ++cnt; }
    }
    tcnt[t] = cnt;
    __syncthreads();
    if (t == 0) {
        int run = 0;
        for (int i = 0; i < 256; ++i) { tbase[i] = run; run += tcnt[i]; }
        *nsel_g = run;
    }
    __syncthreads();
    int base = tbase[t];
    for (int r = 0; r < 32; ++r) {
        if (flags & (1u << r)) {
            const int m = m0 + r;
            sel_idx[base] = m;
            lab_sel[base] = labels[m];
            ++base;
        }
    }
    for (int i = t; i < M_TOT; i += 256) { pos[i] = 0.0f; neg[i] = 0.0f; }
}

// ---------------- kernel 2: L2-normalize selected rows, store transposed -----
__global__ void norm_kernel(const float* __restrict__ features,
                            const int* __restrict__ sel_idx,
                            const int* __restrict__ nsel_g,
                            float* __restrict__ nv_t) {
    const int i = blockIdx.x * 256 + threadIdx.x;
    if (i >= M_TOT) return;
    const int nsel = *nsel_g;
    if (i >= nsel) {
        if (i < TMAX * 64 + 64) {   // zero-pad only what pair tiles can read
            #pragma unroll
            for (int k = 0; k < 64; ++k) nv_t[k * M_TOT + i] = 0.0f;
        }
        return;
    }
    const int m = sel_idx[i];
    float v[64];
    float ss = 0.0f;
    #pragma unroll
    for (int k = 0; k < 64; ++k) {
        v[k] = features[k * M_TOT + m];
        ss += v[k] * v[k];
    }
    const float rn = rsqrtf(ss);
    #pragma unroll
    for (int k = 0; k < 64; ++k) nv_t[k * M_TOT + i] = v[k] * rn;
}

// ---------------- kernel 3: pairwise exp-sim masked row+col sums -------------
// Upper-triangle 64x64 tiles (jt >= it); sim is symmetric so each off-diagonal
// tile contributes its row sums to rows i0.. and its column sums to rows j0..
// 256 threads, 4x4 acc/thread. launch_bounds(256,4): cap VGPR<=128 -> 4 w/EU.
#define EXP2_SCALE 20.609929155556605f   // 1/(0.07*ln2) : exp(s/T)=exp2(s*this)

__global__ __launch_bounds__(256, 4) void pair_kernel(
        const float* __restrict__ nv_t,
        const int* __restrict__ lab_sel,
        const int* __restrict__ nsel_g,
        float* __restrict__ pos,
        float* __restrict__ neg) {
    const int it = blockIdx.y, jt = blockIdx.x;
    if (jt < it) return;                     // symmetry: upper triangle only
    const int nsel = *nsel_g;
    const int i0 = it * 64, j0 = jt * 64;
    if (i0 >= nsel || j0 >= nsel) return;
    const bool offdiag = (jt != it);

    __shared__ float As[64][64];   // [k][i]
    __shared__ float Bs[64][64];   // [k][j]
    __shared__ int   La[64], Lb[64];

    const int t = threadIdx.x;
    #pragma unroll
    for (int r = 0; r < 4; ++r) {
        const int idx = r * 256 + t;
        const int k   = idx >> 4;
        const int c4  = (idx & 15) * 4;
        *(float4*)&As[k][c4] = *(const float4*)&nv_t[k * M_TOT + i0 + c4];
        *(float4*)&Bs[k][c4] = *(const float4*)&nv_t[k * M_TOT + j0 + c4];
    }
    if (t < 64)       La[t]      = (i0 + t < nsel)        ? lab_sel[i0 + t]      : -1;
    else if (t < 128) Lb[t - 64] = (j0 + (t - 64) < nsel) ? lab_sel[j0 + t - 64] : -2;
    __syncthreads();

    const int tx = t & 15, ty = t >> 4;
    float acc[4][4] = {};
    #pragma unroll 8
    for (int k = 0; k < 64; ++k) {
        const float4 a = *(const float4*)&As[k][ty * 4];
        const float4 b = *(const float4*)&Bs[k][tx * 4];
        const float av[4] = {a.x, a.y, a.z, a.w};
        const float bv[4] = {b.x, b.y, b.z, b.w};
        #pragma unroll
        for (int aa = 0; aa < 4; ++aa)
            #pragma unroll
            for (int bb = 0; bb < 4; ++bb)
                acc[aa][bb] += av[aa] * bv[bb];
    }

    float pacc[4] = {0, 0, 0, 0}, nacc[4] = {0, 0, 0, 0};
    float cp[4]   = {0, 0, 0, 0}, cn[4]   = {0, 0, 0, 0};
    #pragma unroll
    for (int aa = 0; aa < 4; ++aa) {
        const int ig = i0 + ty * 4 + aa;
        const int Li = La[ty * 4 + aa];
        #pragma unroll
        for (int bb = 0; bb < 4; ++bb) {
            const int jg = j0 + tx * 4 + bb;
            const bool valid = (ig < nsel) && (jg < nsel) && (ig != jg);
            const float d = valid ? exp2f(acc[aa][bb] * EXP2_SCALE) : 0.0f;
            if (Li == Lb[tx * 4 + bb]) { pacc[aa] += d; cp[bb] += d; }
            else                       { nacc[aa] += d; cn[bb] += d; }
        }
    }

    // ---- row sums: shuffle across the 16 lanes sharing an i-row
    #pragma unroll
    for (int aa = 0; aa < 4; ++aa) {
        float p = pacc[aa], n = nacc[aa];
        for (int off = 8; off > 0; off >>= 1) {
            p += __shfl_down(p, off, 16);
            n += __shfl_down(n, off, 16);
        }
        if (tx == 0) {
            const int ig = i0 + ty * 4 + aa;
            if (ig < nsel) {
                atomicAdd(&pos[ig], p);
                atomicAdd(&neg[ig], n);
            }
        }
    }

    // ---- column sums (off-diagonal tiles only): cross-wave via LDS.
    // Reuse As storage (k-loop reads are done after this barrier).
    if (offdiag) {
        __syncthreads();
        float* colP = &As[0][0];              // [16][65] padded, 1040 floats
        float* colN = colP + 16 * 65;
        #pragma unroll
        for (int bb = 0; bb < 4; ++bb) {
            colP[ty * 65 + tx * 4 + bb] = cp[bb];
            colN[ty * 65 + tx * 4 + bb] = cn[bb];
        }
        __syncthreads();
        if (t < 64) {
            float p = 0.0f, n = 0.0f;
            #pragma unroll
            for (int y = 0; y < 16; ++y) {
                p += colP[y * 65 + t];
                n += colN[y * 65 + t];
            }
            const int jg = j0 + t;
            if (jg < nsel) {
                atomicAdd(&pos[jg], p);
                atomicAdd(&neg[jg], n);
            }
        }
    }
}

// ---------------- kernel 4: final loss reduction -----------------------------
__global__ void loss_kernel(const float* __restrict__ pos,
                            const float* __restrict__ neg,
                            const int* __restrict__ nsel_g,
                            float* __restrict__ out) {
    const int nsel = *nsel_g;
    float s = 0.0f;
    for (int i = threadIdx.x; i < nsel; i += 256) {
        const float fr = pos[i] / (pos[i] + neg[i]);
        s += -logf(fr);
    }
    __shared__ float red[256];
    red[threadIdx.x] = s;
    __syncthreads();
    for (int off = 128; off > 0; off >>= 1) {
        if (threadIdx.x < off) red[threadIdx.x] += red[threadIdx.x + off];
        __syncthreads();
    }
    if (threadIdx.x == 0) out[0] = red[0] / (float)(nsel > 0 ? nsel : 1);
}

// ---------------- launch -----------------------------------------------------
extern "C" void kernel_launch(void* const* d_in, const int* in_sizes, int n_in,
                              void* d_out, int out_size, void* d_ws, size_t ws_size,
                              hipStream_t stream) {
    const float* features = (const float*)d_in[0];
    const int*   labels   = (const int*)d_in[1];
    float*       out      = (float*)d_out;
    char*        ws       = (char*)d_ws;

    int*   nsel_g  = (int*)(ws + 16);
    int*   sel_idx = (int*)(ws + 64);
    int*   lab_sel = (int*)(ws + 64 + 32768);
    float* pos     = (float*)(ws + 64 + 65536);
    float* neg     = pos + M_TOT;
    float* nv_t    = (float*)(ws + 64 + 65536 + 65536);   // 64*8192 fp32 = 2 MiB

    setup_kernel<<<1, 256, 0, stream>>>(labels, nsel_g, sel_idx, lab_sel, pos, neg);
    norm_kernel<<<M_TOT / 256, 256, 0, stream>>>(features, sel_idx, nsel_g, nv_t);
    pair_kernel<<<dim3(TMAX, TMAX), 256, 0, stream>>>(nv_t, lab_sel, nsel_g, pos, neg);
    loss_kernel<<<1, 256, 0, stream>>>(pos, neg, nsel_g, out);
}